// Round 4
// baseline (707.690 us; speedup 1.0000x reference)
//
#include <hip/hip_runtime.h>
#include <stdint.h>

#define D 2560
#define NH 64
#define HD 40
#define TE_ 512
#define FFD 10240
#define TENC 128
#define THID 1024
#define SEQ 1152   // TENC + THID

typedef __bf16 bf16_t;
typedef __bf16 bf16x8 __attribute__((ext_vector_type(8)));
typedef float  f32x4  __attribute__((ext_vector_type(4)));

__device__ __forceinline__ void gld_lds16(const void* g, void* l) {
  __builtin_amdgcn_global_load_lds((__attribute__((address_space(1))) void*)(g),
                                   (__attribute__((address_space(3))) void*)(l), 16, 0, 0);
}

// ---------------- weight transpose+convert: W[K][N] f32 -> Wt[N][K] bf16
__global__ __launch_bounds__(256) void wtrans(const float* __restrict__ W,
                                              bf16_t* __restrict__ Wt, int K, int N) {
  __shared__ float tile[64][65];
  const int bk = blockIdx.x, bn = blockIdx.y, tid = threadIdx.x;
  #pragma unroll
  for (int i = 0; i < 4; ++i) {
    int c = i * 256 + tid;             // 0..1023
    int r = c >> 4, q = c & 15;
    f32x4 v = *(const f32x4*)(W + (size_t)(bk * 64 + r) * N + bn * 64 + q * 4);
    tile[r][q * 4 + 0] = v[0]; tile[r][q * 4 + 1] = v[1];
    tile[r][q * 4 + 2] = v[2]; tile[r][q * 4 + 3] = v[3];
  }
  __syncthreads();
  #pragma unroll
  for (int i = 0; i < 2; ++i) {
    int c = i * 256 + tid;             // 0..511
    int n = c >> 3, kc = c & 7;
    bf16x8 o;
    #pragma unroll
    for (int j = 0; j < 8; ++j) o[j] = (bf16_t)tile[kc * 8 + j][n];
    *(bf16x8*)(Wt + (size_t)(bn * 64 + n) * K + bk * 64 + kc * 8) = o;
  }
}

__global__ void bcat(const float* __restrict__ a, const float* __restrict__ b,
                     const float* __restrict__ c, float* __restrict__ o) {
  int i = blockIdx.x * 256 + threadIdx.x;
  o[i] = i < D ? a[i] : (i < 2 * D ? b[i - D] : c[i - 2 * D]);
}

// ---------------- ada: emb = time_embed @ ada_w + ada_b
__global__ void ada_gemv(const float* __restrict__ te, const float* __restrict__ aw,
                         const float* __restrict__ ab, float* __restrict__ emb) {
  int j = blockIdx.x * 128 + threadIdx.x;
  float acc = ab[j];
  #pragma unroll 8
  for (int k = 0; k < TE_; ++k) acc = fmaf(te[k], aw[(size_t)k * (12 * D) + j], acc);
  emb[j] = acc;
}

// ---------------- LN + adaLN modulation -> bf16 x  (rows 0..127 = encoder)
__global__ void ln_mod(const float* __restrict__ hid, const float* __restrict__ enc,
                       const float* __restrict__ emb, bf16_t* __restrict__ out,
                       int shift_h, int scale_h, int shift_e, int scale_e) {
  int row = blockIdx.x, tid = threadIdx.x;
  const float *src, *sc, *sh;
  if (row < TENC) { src = enc + (size_t)row * D;          sc = emb + scale_e * D; sh = emb + shift_e * D; }
  else            { src = hid + (size_t)(row - TENC) * D; sc = emb + scale_h * D; sh = emb + shift_h * D; }
  float v[10], s = 0.f, s2 = 0.f;
  #pragma unroll
  for (int i = 0; i < 10; ++i) { v[i] = src[tid + i * 256]; s += v[i]; s2 += v[i] * v[i]; }
  #pragma unroll
  for (int o = 32; o > 0; o >>= 1) { s += __shfl_down(s, o); s2 += __shfl_down(s2, o); }
  __shared__ float red[8];
  int wv = tid >> 6, ln = tid & 63;
  if (ln == 0) { red[wv] = s; red[4 + wv] = s2; }
  __syncthreads();
  s  = red[0] + red[1] + red[2] + red[3];
  s2 = red[4] + red[5] + red[6] + red[7];
  float mean = s * (1.f / D);
  float rstd = rsqrtf(s2 * (1.f / D) - mean * mean + 1e-5f);
  #pragma unroll
  for (int i = 0; i < 10; ++i) {
    int c = tid + i * 256;
    out[(size_t)row * D + c] = (bf16_t)((v[i] - mean) * rstd * (1.f + sc[c]) + sh[c]);
  }
}

// ---------------- GEMM v3: C[1152][N] = A_bf16[1152][K] @ Bt_bf16[N][K]^T + bias
// tile 64xBN, 4 waves (2 x 2, each 32 x BN/2), BK=64.
// TRIPLE-buffered: stage(t+2) issued while computing t; counted vmcnt keeps
// next tile's loads in flight across raw s_barrier (T3+T4).
// EPI 0: QKV split-scatter   EPI 1: gelu->bf16   EPI 2: residual+gate->f32
template<int BN, int EPI>
__global__ __launch_bounds__(256) void gemm3(
    const bf16_t* __restrict__ A, const bf16_t* __restrict__ Bt,
    const float* __restrict__ bias, int K, int N, int nM,
    float* __restrict__ outq, float* __restrict__ outk, bf16_t* __restrict__ outv,
    bf16_t* __restrict__ outb,
    const float* __restrict__ emb, int gate_h, int gate_e,
    const float* __restrict__ res_h, const float* __restrict__ res_e,
    float* __restrict__ out_h, float* __restrict__ out_e) {
  constexpr int NB = BN / 32;          // B-fragments per wave (2 or 4)
  constexpr int BCH = BN / 8;          // B chunks per buffer (8 or 16)
  __shared__ bf16_t As[3][64 * 64];
  __shared__ bf16_t Bs[3][BN * 64];
  const int nwg = gridDim.x;
  const int orig = blockIdx.x;
  const int wg = (orig & 7) * (nwg >> 3) + (orig >> 3);   // XCD-chunked swizzle (nwg%8==0)
  const int bm = wg % nM, bn = wg / nM;
  const int m0 = bm * 64, n0 = bn * BN;
  const int tid = threadIdx.x, wv = tid >> 6, ln = tid & 63;
  const int wr = wv >> 1, wc = wv & 1, lr = ln & 15, lg = ln >> 4;

  f32x4 acc[2][NB];
  const f32x4 zero = {0.f, 0.f, 0.f, 0.f};
  #pragma unroll
  for (int m = 0; m < 2; ++m)
    #pragma unroll
    for (int n = 0; n < NB; ++n) acc[m][n] = zero;

  auto stage = [&](int buf, int t) {
    int k0 = t << 6;
    #pragma unroll
    for (int i = 0; i < 2; ++i) {        // A: 64x64 = 8 chunks, 2/wave
      int g = wv * 2 + i;
      int s = g * 64 + ln;
      int r = s >> 3, ks = s & 7;
      gld_lds16(A + (size_t)(m0 + r) * K + k0 + ((ks ^ (r & 7)) << 3), &As[buf][g * 512]);
    }
    #pragma unroll
    for (int i = 0; i < BCH / 4; ++i) {  // Bt: BN x 64 = BCH chunks
      int g = wv * (BCH / 4) + i;
      int s = g * 64 + ln;
      int r = s >> 3, ks = s & 7;
      gld_lds16(Bt + (size_t)(n0 + r) * K + k0 + ((ks ^ (r & 7)) << 3), &Bs[buf][g * 512]);
    }
  };

  const int nt = K >> 6;                 // always >= 40 here
  stage(0, 0);
  stage(1, 1);
  if constexpr (BN == 128) asm volatile("s_waitcnt vmcnt(6)" ::: "memory");
  else                     asm volatile("s_waitcnt vmcnt(4)" ::: "memory");
  asm volatile("s_barrier" ::: "memory");

  int bi = 0;
  for (int t = 0; t < nt; ++t) {
    const bool pre = (t + 2 < nt);
    if (pre) { int sb = bi - 1; if (sb < 0) sb += 3; stage(sb, t + 2); }
    #pragma unroll
    for (int ks = 0; ks < 2; ++ks) {
      int ko = ks * 4 + lg;
      bf16x8 af[2], bfr[NB];
      #pragma unroll
      for (int m = 0; m < 2; ++m) {
        int r = wr * 32 + m * 16 + lr;
        af[m] = *(const bf16x8*)&As[bi][r * 64 + ((ko ^ (r & 7)) << 3)];
      }
      #pragma unroll
      for (int n = 0; n < NB; ++n) {
        int c = wc * (BN / 2) + n * 16 + lr;
        bfr[n] = *(const bf16x8*)&Bs[bi][c * 64 + ((ko ^ (c & 7)) << 3)];
      }
      #pragma unroll
      for (int m = 0; m < 2; ++m)
        #pragma unroll
        for (int n = 0; n < NB; ++n)
          acc[m][n] = __builtin_amdgcn_mfma_f32_16x16x32_bf16(af[m], bfr[n], acc[m][n], 0, 0, 0);
    }
    if (pre) {
      if constexpr (BN == 128) asm volatile("s_waitcnt vmcnt(6) lgkmcnt(0)" ::: "memory");
      else                     asm volatile("s_waitcnt vmcnt(4) lgkmcnt(0)" ::: "memory");
    } else {
      asm volatile("s_waitcnt vmcnt(0) lgkmcnt(0)" ::: "memory");
    }
    asm volatile("s_barrier" ::: "memory");
    bi = (bi == 2) ? 0 : bi + 1;
  }

  #pragma unroll
  for (int m = 0; m < 2; ++m) {
    int row = m0 + wr * 32 + m * 16 + (lg << 2);
    #pragma unroll
    for (int n = 0; n < NB; ++n) {
      int col = n0 + wc * (BN / 2) + n * 16 + lr;
      float bv = bias[col];
      #pragma unroll
      for (int r = 0; r < 4; ++r) {
        float val = acc[m][n][r] + bv;
        int rr = row + r;
        if (EPI == 0) {
          int which = col / D, cc = col - which * D;
          int h = cc / HD, dd = cc - h * HD;
          if (which == 0)      outq[(size_t)h * SEQ * HD + (size_t)rr * HD + dd] = val;
          else if (which == 1) outk[(size_t)h * SEQ * HD + (size_t)rr * HD + dd] = val;
          else                 outv[((size_t)h * 48 + dd) * SEQ + rr] = (bf16_t)val;
        } else if (EPI == 1) {
          float z = 0.7978845608028654f * (val + 0.044715f * val * val * val);
          float t2 = 1.f - 2.f / (__expf(2.f * z) + 1.f);
          outb[(size_t)rr * N + col] = (bf16_t)(0.5f * val * (1.f + t2));
        } else {
          if (rr < TENC) {
            out_e[(size_t)rr * D + col] = res_e[(size_t)rr * D + col] + val * emb[gate_e * D + col];
          } else {
            int r2 = rr - TENC;
            out_h[(size_t)r2 * D + col] = res_h[(size_t)r2 * D + col] + val * emb[gate_h * D + col];
          }
        }
      }
    }
  }
}

// ---------------- per-head LN (+RoPE rows>=128); f32 [h][r][40] -> bf16 [h][r][64] zero-padded
__global__ void qk_post(const float* __restrict__ qh, const float* __restrict__ kh,
                        const float* __restrict__ rc, const float* __restrict__ rs,
                        bf16_t* __restrict__ qb, bf16_t* __restrict__ kb) {
  int r = blockIdx.x * 128 + threadIdx.x;  // 0..1151
  int h = blockIdx.y;
  float cs[HD], sn[HD];
  bool rope = (r >= TENC);
  if (rope) {
    const float* cp = rc + (size_t)(r - TENC) * HD;
    const float* sp = rs + (size_t)(r - TENC) * HD;
    #pragma unroll
    for (int d = 0; d < HD; ++d) { cs[d] = cp[d]; sn[d] = sp[d]; }
  }
  #pragma unroll
  for (int which = 0; which < 2; ++which) {
    const float* base = (which == 0 ? qh : kh) + (size_t)h * SEQ * HD + (size_t)r * HD;
    bf16_t* dst = (which == 0 ? qb : kb) + ((size_t)h * SEQ + r) * 64;
    float v[HD], s = 0.f, s2 = 0.f;
    #pragma unroll
    for (int d = 0; d < HD; ++d) { v[d] = base[d]; s += v[d]; }
    float mean = s * (1.f / HD);
    #pragma unroll
    for (int d = 0; d < HD; ++d) { float x = v[d] - mean; v[d] = x; s2 += x * x; }
    float rstd = rsqrtf(s2 * (1.f / HD) + 1e-5f);
    #pragma unroll
    for (int d = 0; d < HD; ++d) v[d] *= rstd;
    if (rope) {
      #pragma unroll
      for (int d = 0; d < HD / 2; ++d) {
        float lo = v[d], hi = v[d + 20];
        v[d]      = lo * cs[d]      - hi * sn[d];
        v[d + 20] = hi * cs[d + 20] + lo * sn[d + 20];
      }
    }
    float qs = (which == 0) ? 0.15811388300841897f : 1.f;  // 1/sqrt(40)
    #pragma unroll
    for (int d = 0; d < HD; ++d) dst[d] = (bf16_t)(v[d] * qs);
    #pragma unroll
    for (int d = HD; d < 64; ++d) dst[d] = (bf16_t)0.f;
  }
}

// ---------------- MFMA flash attention: block = (64 q-rows, head), 4 waves x 16 q-rows
__global__ __launch_bounds__(256) void attn_mfma(
    const bf16_t* __restrict__ qb, const bf16_t* __restrict__ kb,
    const bf16_t* __restrict__ vt, bf16_t* __restrict__ obf) {
  __shared__ bf16_t Ks[64 * 64];
  __shared__ bf16_t Vs[48 * 64];
  __shared__ bf16_t Ps[4][16 * 64];
  const int h = blockIdx.y;
  const int tid = threadIdx.x, wv = tid >> 6, ln = tid & 63;
  const int qbase = blockIdx.x * 64 + wv * 16;
  const int lr = ln & 15, lg = ln >> 4;

  bf16x8 af[2];
  {
    const bf16_t* qp = qb + ((size_t)h * SEQ + qbase + lr) * 64 + lg * 8;
    af[0] = *(const bf16x8*)(qp);
    af[1] = *(const bf16x8*)(qp + 32);
  }
  const f32x4 zero = {0.f, 0.f, 0.f, 0.f};
  f32x4 acc[3];
  acc[0] = zero; acc[1] = zero; acc[2] = zero;
  float mrow[4], lrow[4];
  #pragma unroll
  for (int r = 0; r < 4; ++r) { mrow[r] = -1e30f; lrow[r] = 0.f; }

  const bf16_t* kbh = kb + (size_t)h * SEQ * 64;
  const bf16_t* vth = vt + (size_t)h * 48 * SEQ;

  for (int kv0 = 0; kv0 < SEQ; kv0 += 64) {
    __syncthreads();
    #pragma unroll
    for (int i = 0; i < 2; ++i) {
      int g = wv * 2 + i;
      int slot = g * 64 + ln;
      int kr = slot >> 3, so = slot & 7;
      gld_lds16(kbh + (size_t)(kv0 + kr) * 64 + ((so ^ (kr & 7)) << 3), &Ks[g * 512]);
    }
    #pragma unroll
    for (int i = 0; i < 2; ++i) {
      int g = wv + 4 * i;
      if (g < 6) {
        int slot = g * 64 + ln;
        int dr = slot >> 3, so = slot & 7;
        gld_lds16(vth + (size_t)dr * SEQ + kv0 + ((so ^ (dr & 7)) << 3), &Vs[g * 512]);
      }
    }
    __syncthreads();
    f32x4 s[4];
    #pragma unroll
    for (int nt = 0; nt < 4; ++nt) {
      s[nt] = zero;
      int kvr = nt * 16 + lr;
      #pragma unroll
      for (int kk = 0; kk < 2; ++kk) {
        bf16x8 bk = *(const bf16x8*)&Ks[kvr * 64 + (((kk * 4 + lg) ^ (kvr & 7)) << 3)];
        s[nt] = __builtin_amdgcn_mfma_f32_16x16x32_bf16(af[kk], bk, s[nt], 0, 0, 0);
      }
    }
    float pn[4][4];
    #pragma unroll
    for (int r = 0; r < 4; ++r) {
      float tm = fmaxf(fmaxf(s[0][r], s[1][r]), fmaxf(s[2][r], s[3][r]));
      #pragma unroll
      for (int o = 8; o > 0; o >>= 1) tm = fmaxf(tm, __shfl_xor(tm, o));
      float mn = fmaxf(mrow[r], tm);
      float scl = __expf(mrow[r] - mn);
      mrow[r] = mn;
      float ts = 0.f;
      #pragma unroll
      for (int nt = 0; nt < 4; ++nt) { pn[nt][r] = __expf(s[nt][r] - mn); ts += pn[nt][r]; }
      #pragma unroll
      for (int o = 8; o > 0; o >>= 1) ts += __shfl_xor(ts, o);
      lrow[r] = lrow[r] * scl + ts;
      acc[0][r] *= scl; acc[1][r] *= scl; acc[2][r] *= scl;
    }
    #pragma unroll
    for (int nt = 0; nt < 4; ++nt)
      #pragma unroll
      for (int r = 0; r < 4; ++r) {
        int q = lg * 4 + r;
        int kv = nt * 16 + lr;
        Ps[wv][q * 64 + ((((kv >> 3) ^ (q & 7)) << 3) | (kv & 7))] = (bf16_t)pn[nt][r];
      }
    bf16x8 pa[2];
    #pragma unroll
    for (int kk = 0; kk < 2; ++kk)
      pa[kk] = *(const bf16x8*)&Ps[wv][lr * 64 + (((kk * 4 + lg) ^ (lr & 7)) << 3)];
    #pragma unroll
    for (int dt = 0; dt < 3; ++dt) {
      #pragma unroll
      for (int kk = 0; kk < 2; ++kk) {
        int dr = dt * 16 + lr;
        bf16x8 bv = *(const bf16x8*)&Vs[dr * 64 + (((kk * 4 + lg) ^ (dr & 7)) << 3)];
        acc[dt] = __builtin_amdgcn_mfma_f32_16x16x32_bf16(pa[kk], bv, acc[dt], 0, 0, 0);
      }
    }
  }
  #pragma unroll
  for (int dt = 0; dt < 3; ++dt) {
    int d = dt * 16 + lr;
    if (d < HD) {
      #pragma unroll
      for (int r = 0; r < 4; ++r) {
        int q = qbase + lg * 4 + r;
        obf[(size_t)q * D + h * HD + d] = (bf16_t)(acc[dt][r] / lrow[r]);
      }
    }
  }
}

extern "C" void kernel_launch(void* const* d_in, const int* in_sizes, int n_in,
                              void* d_out, int out_size, void* d_ws, size_t ws_size,
                              hipStream_t stream) {
  const float* hid = (const float*)d_in[0];
  const float* enc = (const float*)d_in[1];
  const float* tem = (const float*)d_in[2];
  const float* rc  = (const float*)d_in[3];
  const float* rs  = (const float*)d_in[4];
  const float* aw  = (const float*)d_in[5];
  const float* ab  = (const float*)d_in[6];
  const float* wq  = (const float*)d_in[7];
  const float* bq  = (const float*)d_in[8];
  const float* wk  = (const float*)d_in[9];
  const float* bk  = (const float*)d_in[10];
  const float* wvv = (const float*)d_in[11];
  const float* bv  = (const float*)d_in[12];
  const float* wo  = (const float*)d_in[13];
  const float* bo  = (const float*)d_in[14];
  const float* w1  = (const float*)d_in[15];
  const float* b1  = (const float*)d_in[16];
  const float* w2  = (const float*)d_in[17];
  const float* b2  = (const float*)d_in[18];
  float* out_hid = (float*)d_out;
  float* out_enc = out_hid + (size_t)THID * D;

  char* ws = (char*)d_ws;
  size_t off = 0;
  auto alloc = [&](size_t b) { char* p = ws + off; off += (b + 255) & ~(size_t)255; return p; };
  float*  emb  = (float*) alloc((size_t)12 * D * 4);
  bf16_t* xln  = (bf16_t*)alloc((size_t)SEQ * D * 2);          // also attn-out bf16
  float*  qh   = (float*) alloc((size_t)NH * SEQ * HD * 4);    // f32 Q head layout; +kh = FF1 act
  float*  kh   = (float*) alloc((size_t)NH * SEQ * HD * 4);
  bf16_t* vt   = (bf16_t*)alloc((size_t)NH * 48 * SEQ * 2);    // V^T bf16, d padded to 48
  bf16_t* qbb  = (bf16_t*)alloc((size_t)NH * SEQ * 64 * 2);    // Q bf16 padded; +kbb = h1/e1 after attn
  bf16_t* kbb  = (bf16_t*)alloc((size_t)NH * SEQ * 64 * 2);
  bf16_t* wqkvT= (bf16_t*)alloc((size_t)3 * D * D * 2);        // [7680][2560]
  bf16_t* woT  = (bf16_t*)alloc((size_t)D * D * 2);
  bf16_t* w1T  = (bf16_t*)alloc((size_t)FFD * D * 2);          // [10240][2560]
  bf16_t* w2T  = (bf16_t*)alloc((size_t)D * FFD * 2);          // [2560][10240]
  float*  bqkv = (float*) alloc((size_t)3 * D * 4);
  bf16_t* obf = xln;
  bf16_t* aff = (bf16_t*)qh;          // FF1 activation (qh+kh dead after qk_post)
  float*  h1  = (float*)qbb;          // residual-1 hid (qbb/kbb dead after attn)
  float*  e1  = h1 + (size_t)THID * D;

  // weight prep (bf16 + transpose)
  wtrans<<<dim3(40, 40), dim3(256), 0, stream>>>(wq,  wqkvT,                    D, D);
  wtrans<<<dim3(40, 40), dim3(256), 0, stream>>>(wk,  wqkvT + (size_t)D * D,    D, D);
  wtrans<<<dim3(40, 40), dim3(256), 0, stream>>>(wvv, wqkvT + (size_t)2 * D * D,D, D);
  wtrans<<<dim3(40, 40), dim3(256), 0, stream>>>(wo,  woT,                      D, D);
  wtrans<<<dim3(40, 160), dim3(256), 0, stream>>>(w1, w1T, D, FFD);
  wtrans<<<dim3(160, 40), dim3(256), 0, stream>>>(w2, w2T, FFD, D);
  bcat<<<dim3(30), dim3(256), 0, stream>>>(bq, bk, bv, bqkv);

  ada_gemv<<<dim3(240), dim3(128), 0, stream>>>(tem, aw, ab, emb);
  ln_mod<<<dim3(SEQ), dim3(256), 0, stream>>>(hid, enc, emb, xln, 0, 2, 1, 3);
  hipMemsetAsync(vt, 0, (size_t)NH * 48 * SEQ * 2, stream);
  // QKV fused: N=7680, grid 18*60=1080
  gemm3<128, 0><<<dim3(18 * 60), dim3(256), 0, stream>>>(xln, wqkvT, bqkv, D, 3 * D, 18,
      qh, kh, vt, nullptr, nullptr, 0, 0, nullptr, nullptr, nullptr, nullptr);
  qk_post<<<dim3(9, 64), dim3(128), 0, stream>>>(qh, kh, rc, rs, qbb, kbb);
  attn_mfma<<<dim3(18, 64), dim3(256), 0, stream>>>(qbb, kbb, vt, obf);
  // O-proj: 64x64 tiles, grid 18*40=720
  gemm3<64, 2><<<dim3(18 * 40), dim3(256), 0, stream>>>(obf, woT, bo, D, D, 18,
      nullptr, nullptr, nullptr, nullptr, emb, 4, 5, hid, enc, h1, e1);
  ln_mod<<<dim3(SEQ), dim3(256), 0, stream>>>(h1, e1, emb, xln, 6, 8, 7, 9);
  // FF1: grid 18*80=1440
  gemm3<128, 1><<<dim3(18 * 80), dim3(256), 0, stream>>>(xln, w1T, b1, D, FFD, 18,
      nullptr, nullptr, nullptr, aff, nullptr, 0, 0, nullptr, nullptr, nullptr, nullptr);
  // FF2: 64x64 tiles, grid 720
  gemm3<64, 2><<<dim3(18 * 40), dim3(256), 0, stream>>>(aff, w2T, b2, FFD, D, 18,
      nullptr, nullptr, nullptr, nullptr, emb, 10, 11, h1, e1, out_hid, out_enc);
}

// Round 5
// 528.920 us; speedup vs baseline: 1.3380x; 1.3380x over previous
//
#include <hip/hip_runtime.h>
#include <stdint.h>

#define D 2560
#define NH 64
#define HD 40
#define TE_ 512
#define FFD 10240
#define TENC 128
#define THID 1024
#define SEQ 1152   // TENC + THID

typedef __bf16 bf16_t;
typedef __bf16 bf16x8 __attribute__((ext_vector_type(8)));
typedef float  f32x4  __attribute__((ext_vector_type(4)));

__device__ __forceinline__ void gld_lds16(const void* g, void* l) {
  __builtin_amdgcn_global_load_lds((__attribute__((address_space(1))) void*)(g),
                                   (__attribute__((address_space(3))) void*)(l), 16, 0, 0);
}

// ---------------- weight transpose+convert: W[K][N] f32 -> Wt[N][K] bf16
__global__ __launch_bounds__(256) void wtrans(const float* __restrict__ W,
                                              bf16_t* __restrict__ Wt, int K, int N) {
  __shared__ float tile[64][65];
  const int bk = blockIdx.x, bn = blockIdx.y, tid = threadIdx.x;
  #pragma unroll
  for (int i = 0; i < 4; ++i) {
    int c = i * 256 + tid;             // 0..1023
    int r = c >> 4, q = c & 15;
    f32x4 v = *(const f32x4*)(W + (size_t)(bk * 64 + r) * N + bn * 64 + q * 4);
    tile[r][q * 4 + 0] = v[0]; tile[r][q * 4 + 1] = v[1];
    tile[r][q * 4 + 2] = v[2]; tile[r][q * 4 + 3] = v[3];
  }
  __syncthreads();
  #pragma unroll
  for (int i = 0; i < 2; ++i) {
    int c = i * 256 + tid;             // 0..511
    int n = c >> 3, kc = c & 7;
    bf16x8 o;
    #pragma unroll
    for (int j = 0; j < 8; ++j) o[j] = (bf16_t)tile[kc * 8 + j][n];
    *(bf16x8*)(Wt + (size_t)(bn * 64 + n) * K + bk * 64 + kc * 8) = o;
  }
}

__global__ void bcat(const float* __restrict__ a, const float* __restrict__ b,
                     const float* __restrict__ c, float* __restrict__ o) {
  int i = blockIdx.x * 256 + threadIdx.x;
  o[i] = i < D ? a[i] : (i < 2 * D ? b[i - D] : c[i - 2 * D]);
}

// ---------------- ada: emb = time_embed @ ada_w + ada_b
__global__ void ada_gemv(const float* __restrict__ te, const float* __restrict__ aw,
                         const float* __restrict__ ab, float* __restrict__ emb) {
  int j = blockIdx.x * 128 + threadIdx.x;
  float acc = ab[j];
  #pragma unroll 8
  for (int k = 0; k < TE_; ++k) acc = fmaf(te[k], aw[(size_t)k * (12 * D) + j], acc);
  emb[j] = acc;
}

// ---------------- LN + adaLN modulation -> bf16 x  (rows 0..127 = encoder)
__global__ void ln_mod(const float* __restrict__ hid, const float* __restrict__ enc,
                       const float* __restrict__ emb, bf16_t* __restrict__ out,
                       int shift_h, int scale_h, int shift_e, int scale_e) {
  int row = blockIdx.x, tid = threadIdx.x;
  const float *src, *sc, *sh;
  if (row < TENC) { src = enc + (size_t)row * D;          sc = emb + scale_e * D; sh = emb + shift_e * D; }
  else            { src = hid + (size_t)(row - TENC) * D; sc = emb + scale_h * D; sh = emb + shift_h * D; }
  float v[10], s = 0.f, s2 = 0.f;
  #pragma unroll
  for (int i = 0; i < 10; ++i) { v[i] = src[tid + i * 256]; s += v[i]; s2 += v[i] * v[i]; }
  #pragma unroll
  for (int o = 32; o > 0; o >>= 1) { s += __shfl_down(s, o); s2 += __shfl_down(s2, o); }
  __shared__ float red[8];
  int wv = tid >> 6, ln = tid & 63;
  if (ln == 0) { red[wv] = s; red[4 + wv] = s2; }
  __syncthreads();
  s  = red[0] + red[1] + red[2] + red[3];
  s2 = red[4] + red[5] + red[6] + red[7];
  float mean = s * (1.f / D);
  float rstd = rsqrtf(s2 * (1.f / D) - mean * mean + 1e-5f);
  #pragma unroll
  for (int i = 0; i < 10; ++i) {
    int c = tid + i * 256;
    out[(size_t)row * D + c] = (bf16_t)((v[i] - mean) * rstd * (1.f + sc[c]) + sh[c]);
  }
}

// ---------------- GEMM v4 (m97 structure): C[1152][N] = A_bf16 @ Bt_bf16^T
// 128x128 tile, 4 waves (2x2, each 64x64 = 4x4 frags), BK=64, SINGLE-buffered
// 32KB LDS -> 4 blocks/CU; plain 2-barrier loop (implicit wave overlap).
// Optional split-K: nMN = nM*nN tiles per chunk, chunk = wg/nMN.
// EPI 0: QKV split-scatter   EPI 1: gelu->bf16   EPI 4: f32 partial (no bias)
template<int EPI>
__global__ __launch_bounds__(256, 4) void gemm4(
    const bf16_t* __restrict__ A, const bf16_t* __restrict__ Bt,
    const float* __restrict__ bias, int Kld, int ksteps, int N, int nM, int nMN,
    float* __restrict__ outq, float* __restrict__ outk, bf16_t* __restrict__ outv,
    bf16_t* __restrict__ outb, float* __restrict__ outp,
    const float* __restrict__ emb) {
  __shared__ bf16_t As[128 * 64];
  __shared__ bf16_t Bs[128 * 64];
  const int nwg = gridDim.x;
  const int orig = blockIdx.x;
  const int q8 = nwg >> 3, r8 = nwg & 7;
  const int xcd = orig & 7, pos = orig >> 3;
  const int wg = (xcd < r8 ? xcd * (q8 + 1) : r8 * (q8 + 1) + (xcd - r8) * q8) + pos;
  const int part = wg / nMN, rest = wg - part * nMN;
  const int bm = rest % nM, bn = rest / nM;
  const int m0 = bm * 128, n0 = bn * 128;
  const int kbase = part * ksteps;
  const int tid = threadIdx.x, wv = tid >> 6, ln = tid & 63;
  const int wr = wv >> 1, wc = wv & 1, lr = ln & 15, lg = ln >> 4;

  f32x4 acc[4][4];
  const f32x4 zero = {0.f, 0.f, 0.f, 0.f};
  #pragma unroll
  for (int m = 0; m < 4; ++m)
    #pragma unroll
    for (int n = 0; n < 4; ++n) acc[m][n] = zero;

  for (int t = 0; t < ksteps; ++t) {
    const int k0 = (kbase + t) << 6;
    __syncthreads();
    #pragma unroll
    for (int i = 0; i < 4; ++i) {        // A: 128x64 = 16 chunks
      int g = wv * 4 + i;
      int s = g * 64 + ln;
      int r = s >> 3, ks = s & 7;
      gld_lds16(A + (size_t)(m0 + r) * Kld + k0 + ((ks ^ (r & 7)) << 3), &As[g * 512]);
    }
    #pragma unroll
    for (int i = 0; i < 4; ++i) {        // Bt: 128x64 = 16 chunks
      int g = wv * 4 + i;
      int s = g * 64 + ln;
      int r = s >> 3, ks = s & 7;
      gld_lds16(Bt + (size_t)(n0 + r) * Kld + k0 + ((ks ^ (r & 7)) << 3), &Bs[g * 512]);
    }
    __syncthreads();                     // drains vmcnt(0) before reads
    #pragma unroll
    for (int ks2 = 0; ks2 < 2; ++ks2) {
      int ko = ks2 * 4 + lg;
      bf16x8 af[4], bfr[4];
      #pragma unroll
      for (int m = 0; m < 4; ++m) {
        int r = wr * 64 + m * 16 + lr;
        af[m] = *(const bf16x8*)&As[r * 64 + ((ko ^ (r & 7)) << 3)];
      }
      #pragma unroll
      for (int n = 0; n < 4; ++n) {
        int c = wc * 64 + n * 16 + lr;
        bfr[n] = *(const bf16x8*)&Bs[c * 64 + ((ko ^ (c & 7)) << 3)];
      }
      #pragma unroll
      for (int m = 0; m < 4; ++m)
        #pragma unroll
        for (int n = 0; n < 4; ++n)
          acc[m][n] = __builtin_amdgcn_mfma_f32_16x16x32_bf16(af[m], bfr[n], acc[m][n], 0, 0, 0);
    }
  }

  #pragma unroll
  for (int m = 0; m < 4; ++m) {
    int row = m0 + wr * 64 + m * 16 + (lg << 2);
    #pragma unroll
    for (int n = 0; n < 4; ++n) {
      int col = n0 + wc * 64 + n * 16 + lr;
      float bv = (EPI == 4) ? 0.f : bias[col];
      #pragma unroll
      for (int r = 0; r < 4; ++r) {
        float val = acc[m][n][r] + bv;
        int rr = row + r;
        if (EPI == 0) {
          int which = col / D, cc = col - which * D;
          int h = cc / HD, dd = cc - h * HD;
          if (which == 0)      outq[(size_t)h * SEQ * HD + (size_t)rr * HD + dd] = val;
          else if (which == 1) outk[(size_t)h * SEQ * HD + (size_t)rr * HD + dd] = val;
          else                 outv[((size_t)h * 48 + dd) * SEQ + rr] = (bf16_t)val;
        } else if (EPI == 1) {
          float z = 0.7978845608028654f * (val + 0.044715f * val * val * val);
          float t2 = 1.f - 2.f / (__expf(2.f * z) + 1.f);
          outb[(size_t)rr * N + col] = (bf16_t)(0.5f * val * (1.f + t2));
        } else {
          outp[(size_t)part * SEQ * N + (size_t)rr * N + col] = val;
        }
      }
    }
  }
}

// ---------------- split-K reduce + bias + gate + residual -> f32 out
template<int P>
__global__ void redk(const float* __restrict__ parts, const float* __restrict__ bias,
                     const float* __restrict__ emb, int gate_h, int gate_e,
                     const float* __restrict__ res_h, const float* __restrict__ res_e,
                     float* __restrict__ out_h, float* __restrict__ out_e) {
  int idx = blockIdx.x * 256 + threadIdx.x;      // over SEQ*D/4
  int row = idx / (D / 4), col = (idx - row * (D / 4)) * 4;
  f32x4 s = *(const f32x4*)(bias + col);
  #pragma unroll
  for (int p = 0; p < P; ++p)
    s += *(const f32x4*)(parts + (size_t)p * SEQ * D + (size_t)row * D + col);
  const float* res; float* out; int g;
  int r2;
  if (row < TENC) { res = res_e; out = out_e; g = gate_e; r2 = row; }
  else            { res = res_h; out = out_h; g = gate_h; r2 = row - TENC; }
  f32x4 g4 = *(const f32x4*)(emb + (size_t)g * D + col);
  f32x4 rr4 = *(const f32x4*)(res + (size_t)r2 * D + col);
  f32x4 o;
  #pragma unroll
  for (int j = 0; j < 4; ++j) o[j] = rr4[j] + s[j] * g4[j];
  *(f32x4*)(out + (size_t)r2 * D + col) = o;
}

// ---------------- per-head LN (+RoPE rows>=128); f32 [h][r][40] -> bf16 [h][r][64] zero-padded
__global__ void qk_post(const float* __restrict__ qh, const float* __restrict__ kh,
                        const float* __restrict__ rc, const float* __restrict__ rs,
                        bf16_t* __restrict__ qb, bf16_t* __restrict__ kb) {
  int r = blockIdx.x * 128 + threadIdx.x;  // 0..1151
  int h = blockIdx.y;
  float cs[HD], sn[HD];
  bool rope = (r >= TENC);
  if (rope) {
    const float* cp = rc + (size_t)(r - TENC) * HD;
    const float* sp = rs + (size_t)(r - TENC) * HD;
    #pragma unroll
    for (int d = 0; d < HD; ++d) { cs[d] = cp[d]; sn[d] = sp[d]; }
  }
  #pragma unroll
  for (int which = 0; which < 2; ++which) {
    const float* base = (which == 0 ? qh : kh) + (size_t)h * SEQ * HD + (size_t)r * HD;
    bf16_t* dst = (which == 0 ? qb : kb) + ((size_t)h * SEQ + r) * 64;
    float v[HD], s = 0.f, s2 = 0.f;
    #pragma unroll
    for (int d = 0; d < HD; ++d) { v[d] = base[d]; s += v[d]; }
    float mean = s * (1.f / HD);
    #pragma unroll
    for (int d = 0; d < HD; ++d) { float x = v[d] - mean; v[d] = x; s2 += x * x; }
    float rstd = rsqrtf(s2 * (1.f / HD) + 1e-5f);
    #pragma unroll
    for (int d = 0; d < HD; ++d) v[d] *= rstd;
    if (rope) {
      #pragma unroll
      for (int d = 0; d < HD / 2; ++d) {
        float lo = v[d], hi = v[d + 20];
        v[d]      = lo * cs[d]      - hi * sn[d];
        v[d + 20] = hi * cs[d + 20] + lo * sn[d + 20];
      }
    }
    float qs = (which == 0) ? 0.15811388300841897f : 1.f;  // 1/sqrt(40)
    #pragma unroll
    for (int d = 0; d < HD; ++d) dst[d] = (bf16_t)(v[d] * qs);
    #pragma unroll
    for (int d = HD; d < 64; ++d) dst[d] = (bf16_t)0.f;
  }
}

// ---------------- MFMA flash attention: block = (64 q-rows, head), 4 waves x 16 q-rows
__global__ __launch_bounds__(256) void attn_mfma(
    const bf16_t* __restrict__ qb, const bf16_t* __restrict__ kb,
    const bf16_t* __restrict__ vt, bf16_t* __restrict__ obf) {
  __shared__ bf16_t Ks[64 * 64];
  __shared__ bf16_t Vs[48 * 64];
  __shared__ bf16_t Ps[4][16 * 64];
  const int h = blockIdx.y;
  const int tid = threadIdx.x, wv = tid >> 6, ln = tid & 63;
  const int qbase = blockIdx.x * 64 + wv * 16;
  const int lr = ln & 15, lg = ln >> 4;

  bf16x8 af[2];
  {
    const bf16_t* qp = qb + ((size_t)h * SEQ + qbase + lr) * 64 + lg * 8;
    af[0] = *(const bf16x8*)(qp);
    af[1] = *(const bf16x8*)(qp + 32);
  }
  const f32x4 zero = {0.f, 0.f, 0.f, 0.f};
  f32x4 acc[3];
  acc[0] = zero; acc[1] = zero; acc[2] = zero;
  float mrow[4], lrow[4];
  #pragma unroll
  for (int r = 0; r < 4; ++r) { mrow[r] = -1e30f; lrow[r] = 0.f; }

  const bf16_t* kbh = kb + (size_t)h * SEQ * 64;
  const bf16_t* vth = vt + (size_t)h * 48 * SEQ;

  for (int kv0 = 0; kv0 < SEQ; kv0 += 64) {
    __syncthreads();
    #pragma unroll
    for (int i = 0; i < 2; ++i) {
      int g = wv * 2 + i;
      int slot = g * 64 + ln;
      int kr = slot >> 3, so = slot & 7;
      gld_lds16(kbh + (size_t)(kv0 + kr) * 64 + ((so ^ (kr & 7)) << 3), &Ks[g * 512]);
    }
    #pragma unroll
    for (int i = 0; i < 2; ++i) {
      int g = wv + 4 * i;
      if (g < 6) {
        int slot = g * 64 + ln;
        int dr = slot >> 3, so = slot & 7;
        gld_lds16(vth + (size_t)dr * SEQ + kv0 + ((so ^ (dr & 7)) << 3), &Vs[g * 512]);
      }
    }
    __syncthreads();
    f32x4 s[4];
    #pragma unroll
    for (int nt = 0; nt < 4; ++nt) {
      s[nt] = zero;
      int kvr = nt * 16 + lr;
      #pragma unroll
      for (int kk = 0; kk < 2; ++kk) {
        bf16x8 bk = *(const bf16x8*)&Ks[kvr * 64 + (((kk * 4 + lg) ^ (kvr & 7)) << 3)];
        s[nt] = __builtin_amdgcn_mfma_f32_16x16x32_bf16(af[kk], bk, s[nt], 0, 0, 0);
      }
    }
    float pn[4][4];
    #pragma unroll
    for (int r = 0; r < 4; ++r) {
      float tm = fmaxf(fmaxf(s[0][r], s[1][r]), fmaxf(s[2][r], s[3][r]));
      #pragma unroll
      for (int o = 8; o > 0; o >>= 1) tm = fmaxf(tm, __shfl_xor(tm, o));
      float mn = fmaxf(mrow[r], tm);
      float scl = __expf(mrow[r] - mn);
      mrow[r] = mn;
      float ts = 0.f;
      #pragma unroll
      for (int nt = 0; nt < 4; ++nt) { pn[nt][r] = __expf(s[nt][r] - mn); ts += pn[nt][r]; }
      #pragma unroll
      for (int o = 8; o > 0; o >>= 1) ts += __shfl_xor(ts, o);
      lrow[r] = lrow[r] * scl + ts;
      acc[0][r] *= scl; acc[1][r] *= scl; acc[2][r] *= scl;
    }
    #pragma unroll
    for (int nt = 0; nt < 4; ++nt)
      #pragma unroll
      for (int r = 0; r < 4; ++r) {
        int q = lg * 4 + r;
        int kv = nt * 16 + lr;
        Ps[wv][q * 64 + ((((kv >> 3) ^ (q & 7)) << 3) | (kv & 7))] = (bf16_t)pn[nt][r];
      }
    bf16x8 pa[2];
    #pragma unroll
    for (int kk = 0; kk < 2; ++kk)
      pa[kk] = *(const bf16x8*)&Ps[wv][lr * 64 + (((kk * 4 + lg) ^ (lr & 7)) << 3)];
    #pragma unroll
    for (int dt = 0; dt < 3; ++dt) {
      #pragma unroll
      for (int kk = 0; kk < 2; ++kk) {
        int dr = dt * 16 + lr;
        bf16x8 bv = *(const bf16x8*)&Vs[dr * 64 + (((kk * 4 + lg) ^ (dr & 7)) << 3)];
        acc[dt] = __builtin_amdgcn_mfma_f32_16x16x32_bf16(pa[kk], bv, acc[dt], 0, 0, 0);
      }
    }
  }
  #pragma unroll
  for (int dt = 0; dt < 3; ++dt) {
    int d = dt * 16 + lr;
    if (d < HD) {
      #pragma unroll
      for (int r = 0; r < 4; ++r) {
        int q = qbase + lg * 4 + r;
        obf[(size_t)q * D + h * HD + d] = (bf16_t)(acc[dt][r] / lrow[r]);
      }
    }
  }
}

extern "C" void kernel_launch(void* const* d_in, const int* in_sizes, int n_in,
                              void* d_out, int out_size, void* d_ws, size_t ws_size,
                              hipStream_t stream) {
  const float* hid = (const float*)d_in[0];
  const float* enc = (const float*)d_in[1];
  const float* tem = (const float*)d_in[2];
  const float* rc  = (const float*)d_in[3];
  const float* rs  = (const float*)d_in[4];
  const float* aw  = (const float*)d_in[5];
  const float* ab  = (const float*)d_in[6];
  const float* wq  = (const float*)d_in[7];
  const float* bq  = (const float*)d_in[8];
  const float* wk  = (const float*)d_in[9];
  const float* bk  = (const float*)d_in[10];
  const float* wvv = (const float*)d_in[11];
  const float* bv  = (const float*)d_in[12];
  const float* wo  = (const float*)d_in[13];
  const float* bo  = (const float*)d_in[14];
  const float* w1  = (const float*)d_in[15];
  const float* b1  = (const float*)d_in[16];
  const float* w2  = (const float*)d_in[17];
  const float* b2  = (const float*)d_in[18];
  float* out_hid = (float*)d_out;
  float* out_enc = out_hid + (size_t)THID * D;

  char* ws = (char*)d_ws;
  size_t off = 0;
  auto alloc = [&](size_t b) { char* p = ws + off; off += (b + 255) & ~(size_t)255; return p; };
  float*  emb  = (float*) alloc((size_t)12 * D * 4);
  bf16_t* xln  = (bf16_t*)alloc((size_t)SEQ * D * 2);          // also attn-out bf16
  float*  qh   = (float*) alloc((size_t)NH * SEQ * HD * 4);    // f32 Q head layout; +kh = FF1 act
  float*  kh   = (float*) alloc((size_t)NH * SEQ * HD * 4);
  bf16_t* vt   = (bf16_t*)alloc((size_t)NH * 48 * SEQ * 2);    // V^T bf16, d padded to 48
  bf16_t* qbb  = (bf16_t*)alloc((size_t)NH * SEQ * 64 * 2);    // Q bf16 padded; +kbb = h1/e1 after attn
  bf16_t* kbb  = (bf16_t*)alloc((size_t)NH * SEQ * 64 * 2);
  bf16_t* wqkvT= (bf16_t*)alloc((size_t)3 * D * D * 2);        // [7680][2560] (39.3 MB)
  bf16_t* woT  = (bf16_t*)alloc((size_t)D * D * 2);            // contiguous after wqkvT
  bf16_t* w1T  = (bf16_t*)alloc((size_t)FFD * D * 2);          // [10240][2560]
  bf16_t* w2T  = (bf16_t*)alloc((size_t)D * FFD * 2);          // [2560][10240]
  float*  bqkv = (float*) alloc((size_t)3 * D * 4);
  bf16_t* obf = xln;
  bf16_t* aff = (bf16_t*)qh;          // FF1 activation (qh+kh dead after qk_post)
  float*  h1  = (float*)qbb;          // residual-1 hid (qbb/kbb dead after attn)
  float*  e1  = h1 + (size_t)THID * D;
  float*  oparts = (float*)wqkvT;     // O-proj partials 2x11.8MB (wqkvT dead after QKV)
  float*  fparts = (float*)wqkvT;     // FF2 partials 4x11.8MB (spills into dead woT)

  // weight prep (bf16 + transpose)
  wtrans<<<dim3(40, 40), dim3(256), 0, stream>>>(wq,  wqkvT,                    D, D);
  wtrans<<<dim3(40, 40), dim3(256), 0, stream>>>(wk,  wqkvT + (size_t)D * D,    D, D);
  wtrans<<<dim3(40, 40), dim3(256), 0, stream>>>(wvv, wqkvT + (size_t)2 * D * D,D, D);
  wtrans<<<dim3(40, 40), dim3(256), 0, stream>>>(wo,  woT,                      D, D);
  wtrans<<<dim3(40, 160), dim3(256), 0, stream>>>(w1, w1T, D, FFD);
  wtrans<<<dim3(160, 40), dim3(256), 0, stream>>>(w2, w2T, FFD, D);
  bcat<<<dim3(30), dim3(256), 0, stream>>>(bq, bk, bv, bqkv);

  ada_gemv<<<dim3(240), dim3(128), 0, stream>>>(tem, aw, ab, emb);
  ln_mod<<<dim3(SEQ), dim3(256), 0, stream>>>(hid, enc, emb, xln, 0, 2, 1, 3);
  hipMemsetAsync(vt, 0, (size_t)NH * 48 * SEQ * 2, stream);
  // QKV fused: N=7680, grid 9*60=540
  gemm4<0><<<dim3(540), dim3(256), 0, stream>>>(xln, wqkvT, bqkv, D, 40, 3 * D, 9, 540,
      qh, kh, vt, nullptr, nullptr, nullptr);
  qk_post<<<dim3(9, 64), dim3(128), 0, stream>>>(qh, kh, rc, rs, qbb, kbb);
  attn_mfma<<<dim3(18, 64), dim3(256), 0, stream>>>(qbb, kbb, vt, obf);
  // O-proj: split-K x2, grid 9*20*2=360 -> partials, then reduce (bias+gate+res)
  gemm4<4><<<dim3(360), dim3(256), 0, stream>>>(obf, woT, nullptr, D, 20, D, 9, 180,
      nullptr, nullptr, nullptr, nullptr, oparts, nullptr);
  redk<2><<<dim3(2880), dim3(256), 0, stream>>>(oparts, bo, emb, 4, 5, hid, enc, h1, e1);
  ln_mod<<<dim3(SEQ), dim3(256), 0, stream>>>(h1, e1, emb, xln, 6, 8, 7, 9);
  // FF1: N=10240, grid 9*80=720
  gemm4<1><<<dim3(720), dim3(256), 0, stream>>>(xln, w1T, b1, D, 40, FFD, 9, 720,
      nullptr, nullptr, nullptr, aff, nullptr, nullptr);
  // FF2: K=10240 split-K x4, grid 9*20*4=720 -> partials, then reduce
  gemm4<4><<<dim3(720), dim3(256), 0, stream>>>(aff, w2T, nullptr, FFD, 40, D, 9, 180,
      nullptr, nullptr, nullptr, nullptr, fparts, nullptr);
  redk<4><<<dim3(2880), dim3(256), 0, stream>>>(fparts, b2, emb, 10, 11, h1, e1, out_hid, out_enc);
}

// Round 6
// 475.092 us; speedup vs baseline: 1.4896x; 1.1133x over previous
//
#include <hip/hip_runtime.h>
#include <stdint.h>

#define D 2560
#define NH 64
#define HD 40
#define TE_ 512
#define FFD 10240
#define TENC 128
#define THID 1024
#define SEQ 1152   // TENC + THID

typedef __bf16 bf16_t;
typedef __bf16 bf16x8 __attribute__((ext_vector_type(8)));
typedef float  f32x4  __attribute__((ext_vector_type(4)));

__device__ __forceinline__ void gld_lds16(const void* g, void* l) {
  __builtin_amdgcn_global_load_lds((__attribute__((address_space(1))) void*)(g),
                                   (__attribute__((address_space(3))) void*)(l), 16, 0, 0);
}

// ---------------- weight transpose+convert tile: W[K][N] f32 -> Wt[N][K] bf16
__device__ __forceinline__ void wtrans_tile(const float* __restrict__ W, bf16_t* __restrict__ Wt,
                                            int K, int N, int bk, int bn, int tid,
                                            float* tile /* 64*65 f32 */) {
  #pragma unroll
  for (int i = 0; i < 4; ++i) {
    int c = i * 256 + tid;             // 0..1023
    int r = c >> 4, q = c & 15;
    f32x4 v = *(const f32x4*)(W + (size_t)(bk * 64 + r) * N + bn * 64 + q * 4);
    tile[r * 65 + q * 4 + 0] = v[0]; tile[r * 65 + q * 4 + 1] = v[1];
    tile[r * 65 + q * 4 + 2] = v[2]; tile[r * 65 + q * 4 + 3] = v[3];
  }
  __syncthreads();
  #pragma unroll
  for (int i = 0; i < 2; ++i) {
    int c = i * 256 + tid;             // 0..511
    int n = c >> 3, kc = c & 7;
    bf16x8 o;
    #pragma unroll
    for (int j = 0; j < 8; ++j) o[j] = (bf16_t)tile[(kc * 8 + j) * 65 + n];
    *(bf16x8*)(Wt + (size_t)(bn * 64 + n) * K + bk * 64 + kc * 8) = o;
  }
}

// ---------------- prep1: ada GEMV + 4 DxD weight transposes + bias concat + vt zero
// block roles: [0,120) ada | [120,1720) wq | [1720,3320) wk | [3320,4920) wv
//              [4920,6520) wo | [6520,6550) bcat | [6550,8278) vt zero
__global__ __launch_bounds__(256) void prep1(
    const float* __restrict__ te, const float* __restrict__ aw, const float* __restrict__ ab,
    float* __restrict__ emb,
    const float* __restrict__ wq, const float* __restrict__ wk,
    const float* __restrict__ wv, const float* __restrict__ wo,
    bf16_t* __restrict__ wqkvT, bf16_t* __restrict__ woT,
    const float* __restrict__ bq, const float* __restrict__ bk, const float* __restrict__ bv,
    float* __restrict__ bqkv, bf16_t* __restrict__ vt) {
  __shared__ float tile[64 * 65];
  const int b = blockIdx.x, t = threadIdx.x;
  if (b < 120) {
    int j = b * 256 + t;
    float acc = ab[j];
    #pragma unroll 8
    for (int k = 0; k < TE_; ++k) acc = fmaf(te[k], aw[(size_t)k * (12 * D) + j], acc);
    emb[j] = acc;
  } else if (b < 1720) {
    int l = b - 120;  wtrans_tile(wq, wqkvT,                     D, D, l % 40, l / 40, t, tile);
  } else if (b < 3320) {
    int l = b - 1720; wtrans_tile(wk, wqkvT + (size_t)D * D,     D, D, l % 40, l / 40, t, tile);
  } else if (b < 4920) {
    int l = b - 3320; wtrans_tile(wv, wqkvT + (size_t)2 * D * D, D, D, l % 40, l / 40, t, tile);
  } else if (b < 6520) {
    int l = b - 4920; wtrans_tile(wo, woT,                       D, D, l % 40, l / 40, t, tile);
  } else if (b < 6550) {
    int i = (b - 6520) * 256 + t;
    bqkv[i] = i < D ? bq[i] : (i < 2 * D ? bk[i - D] : bv[i - 2 * D]);
  } else {
    int i = (b - 6550) * 256 + t;      // 442368 granules of 8 bf16 = 64*48*1152
    bf16x8 z = {};
    *(bf16x8*)(vt + (size_t)i * 8) = z;
  }
}

// ---------------- LN + adaLN modulation -> bf16 x  (rows 0..127 = encoder)
__global__ void ln_mod(const float* __restrict__ hid, const float* __restrict__ enc,
                       const float* __restrict__ emb, bf16_t* __restrict__ out,
                       int shift_h, int scale_h, int shift_e, int scale_e) {
  int row = blockIdx.x, tid = threadIdx.x;
  const float *src, *sc, *sh;
  if (row < TENC) { src = enc + (size_t)row * D;          sc = emb + scale_e * D; sh = emb + shift_e * D; }
  else            { src = hid + (size_t)(row - TENC) * D; sc = emb + scale_h * D; sh = emb + shift_h * D; }
  float v[10], s = 0.f, s2 = 0.f;
  #pragma unroll
  for (int i = 0; i < 10; ++i) { v[i] = src[tid + i * 256]; s += v[i]; s2 += v[i] * v[i]; }
  #pragma unroll
  for (int o = 32; o > 0; o >>= 1) { s += __shfl_down(s, o); s2 += __shfl_down(s2, o); }
  __shared__ float red[8];
  int wv = tid >> 6, ln = tid & 63;
  if (ln == 0) { red[wv] = s; red[4 + wv] = s2; }
  __syncthreads();
  s  = red[0] + red[1] + red[2] + red[3];
  s2 = red[4] + red[5] + red[6] + red[7];
  float mean = s * (1.f / D);
  float rstd = rsqrtf(s2 * (1.f / D) - mean * mean + 1e-5f);
  #pragma unroll
  for (int i = 0; i < 10; ++i) {
    int c = tid + i * 256;
    out[(size_t)row * D + c] = (bf16_t)((v[i] - mean) * rstd * (1.f + sc[c]) + sh[c]);
  }
}

// ---------------- GEMM body (m97 structure): C[1152][N] = A_bf16 @ Bt_bf16^T
// 128x128 tile, 4 waves (2x2, each 64x64 = 4x4 frags), BK=64, single-buffered.
// EPI 0: QKV split-scatter   EPI 1: gelu->bf16   EPI 4: f32 partial (no bias)
template<int EPI>
__device__ __forceinline__ void gemm_body(
    bf16_t* As, bf16_t* Bs,
    const bf16_t* __restrict__ A, const bf16_t* __restrict__ Bt,
    const float* __restrict__ bias, int Kld, int ksteps, int N, int nM, int nMN,
    int nwg, int orig,
    float* __restrict__ outq, float* __restrict__ outk, bf16_t* __restrict__ outv,
    bf16_t* __restrict__ outb, float* __restrict__ outp) {
  const int q8 = nwg >> 3, r8 = nwg & 7;
  const int xcd = orig & 7, pos = orig >> 3;
  const int wg = (xcd < r8 ? xcd * (q8 + 1) : r8 * (q8 + 1) + (xcd - r8) * q8) + pos;
  const int part = wg / nMN, rest = wg - part * nMN;
  const int bm = rest % nM, bn = rest / nM;
  const int m0 = bm * 128, n0 = bn * 128;
  const int kbase = part * ksteps;
  const int tid = threadIdx.x, wv = tid >> 6, ln = tid & 63;
  const int wr = wv >> 1, wc = wv & 1, lr = ln & 15, lg = ln >> 4;

  f32x4 acc[4][4];
  const f32x4 zero = {0.f, 0.f, 0.f, 0.f};
  #pragma unroll
  for (int m = 0; m < 4; ++m)
    #pragma unroll
    for (int n = 0; n < 4; ++n) acc[m][n] = zero;

  for (int t = 0; t < ksteps; ++t) {
    const int k0 = (kbase + t) << 6;
    __syncthreads();
    #pragma unroll
    for (int i = 0; i < 4; ++i) {        // A: 128x64 = 16 chunks
      int g = wv * 4 + i;
      int s = g * 64 + ln;
      int r = s >> 3, ks = s & 7;
      gld_lds16(A + (size_t)(m0 + r) * Kld + k0 + ((ks ^ (r & 7)) << 3), &As[g * 512]);
    }
    #pragma unroll
    for (int i = 0; i < 4; ++i) {        // Bt: 128x64 = 16 chunks
      int g = wv * 4 + i;
      int s = g * 64 + ln;
      int r = s >> 3, ks = s & 7;
      gld_lds16(Bt + (size_t)(n0 + r) * Kld + k0 + ((ks ^ (r & 7)) << 3), &Bs[g * 512]);
    }
    __syncthreads();                     // drains vmcnt(0) before reads
    #pragma unroll
    for (int ks2 = 0; ks2 < 2; ++ks2) {
      int ko = ks2 * 4 + lg;
      bf16x8 af[4], bfr[4];
      #pragma unroll
      for (int m = 0; m < 4; ++m) {
        int r = wr * 64 + m * 16 + lr;
        af[m] = *(const bf16x8*)&As[r * 64 + ((ko ^ (r & 7)) << 3)];
      }
      #pragma unroll
      for (int n = 0; n < 4; ++n) {
        int c = wc * 64 + n * 16 + lr;
        bfr[n] = *(const bf16x8*)&Bs[c * 64 + ((ko ^ (c & 7)) << 3)];
      }
      #pragma unroll
      for (int m = 0; m < 4; ++m)
        #pragma unroll
        for (int n = 0; n < 4; ++n)
          acc[m][n] = __builtin_amdgcn_mfma_f32_16x16x32_bf16(af[m], bfr[n], acc[m][n], 0, 0, 0);
    }
  }

  #pragma unroll
  for (int m = 0; m < 4; ++m) {
    int row = m0 + wr * 64 + m * 16 + (lg << 2);
    #pragma unroll
    for (int n = 0; n < 4; ++n) {
      int col = n0 + wc * 64 + n * 16 + lr;
      float bv = (EPI == 4) ? 0.f : bias[col];
      #pragma unroll
      for (int r = 0; r < 4; ++r) {
        float val = acc[m][n][r] + bv;
        int rr = row + r;
        if (EPI == 0) {
          int which = col / D, cc = col - which * D;
          int h = cc / HD, dd = cc - h * HD;
          if (which == 0)      outq[(size_t)h * SEQ * HD + (size_t)rr * HD + dd] = val;
          else if (which == 1) outk[(size_t)h * SEQ * HD + (size_t)rr * HD + dd] = val;
          else                 outv[((size_t)h * 48 + dd) * SEQ + rr] = (bf16_t)val;
        } else if (EPI == 1) {
          float z = 0.7978845608028654f * (val + 0.044715f * val * val * val);
          float t2 = 1.f - 2.f / (__expf(2.f * z) + 1.f);
          outb[(size_t)rr * N + col] = (bf16_t)(0.5f * val * (1.f + t2));
        } else {
          outp[(size_t)part * SEQ * N + (size_t)rr * N + col] = val;
        }
      }
    }
  }
}

template<int EPI>
__global__ __launch_bounds__(256, 4) void gemm4(
    const bf16_t* __restrict__ A, const bf16_t* __restrict__ Bt,
    const float* __restrict__ bias, int Kld, int ksteps, int N, int nM, int nMN,
    float* __restrict__ outq, float* __restrict__ outk, bf16_t* __restrict__ outv,
    bf16_t* __restrict__ outb, float* __restrict__ outp) {
  __shared__ bf16_t As[128 * 64];
  __shared__ bf16_t Bs[128 * 64];
  gemm_body<EPI>(As, Bs, A, Bt, bias, Kld, ksteps, N, nM, nMN, gridDim.x, blockIdx.x,
                 outq, outk, outv, outb, outp);
}

// ---------------- QKV GEMM + w1/w2 transposes riding along (needed 2 launches later)
// roles: [0,540) QKV gemm | [540,6940) w1T (40x160) | [6940,13340) w2T (160x40)
__global__ __launch_bounds__(256, 4) void qkv_plus(
    const bf16_t* __restrict__ A, const bf16_t* __restrict__ wqkvT,
    const float* __restrict__ bqkv,
    float* __restrict__ outq, float* __restrict__ outk, bf16_t* __restrict__ outv,
    const float* __restrict__ w1, bf16_t* __restrict__ w1T,
    const float* __restrict__ w2, bf16_t* __restrict__ w2T) {
  __shared__ char smem[32768] __attribute__((aligned(16)));
  const int b = blockIdx.x;
  if (b < 540) {
    gemm_body<0>((bf16_t*)smem, (bf16_t*)(smem + 16384), A, wqkvT, bqkv,
                 D, 40, 3 * D, 9, 540, 540, b, outq, outk, outv, nullptr, nullptr);
  } else if (b < 6940) {
    int l = b - 540;
    wtrans_tile(w1, w1T, D, FFD, l % 40, l / 40, threadIdx.x, (float*)smem);
  } else {
    int l = b - 6940;
    wtrans_tile(w2, w2T, FFD, D, l % 160, l / 160, threadIdx.x, (float*)smem);
  }
}

// ---------------- split-K reduce + bias + gate + residual -> f32 out (final)
template<int P>
__global__ void redk(const float* __restrict__ parts, const float* __restrict__ bias,
                     const float* __restrict__ emb, int gate_h, int gate_e,
                     const float* __restrict__ res_h, const float* __restrict__ res_e,
                     float* __restrict__ out_h, float* __restrict__ out_e) {
  int idx = blockIdx.x * 256 + threadIdx.x;      // over SEQ*D/4
  int row = idx / (D / 4), col = (idx - row * (D / 4)) * 4;
  f32x4 s = *(const f32x4*)(bias + col);
  #pragma unroll
  for (int p = 0; p < P; ++p)
    s += *(const f32x4*)(parts + (size_t)p * SEQ * D + (size_t)row * D + col);
  const float* res; float* out; int g;
  int r2;
  if (row < TENC) { res = res_e; out = out_e; g = gate_e; r2 = row; }
  else            { res = res_h; out = out_h; g = gate_h; r2 = row - TENC; }
  f32x4 g4 = *(const f32x4*)(emb + (size_t)g * D + col);
  f32x4 rr4 = *(const f32x4*)(res + (size_t)r2 * D + col);
  f32x4 o;
  #pragma unroll
  for (int j = 0; j < 4; ++j) o[j] = rr4[j] + s[j] * g4[j];
  *(f32x4*)(out + (size_t)r2 * D + col) = o;
}

// ---------------- split-K reduce + bias + gate + residual -> h1/e1 f32, THEN LN+mod -> xln bf16
template<int P>
__global__ __launch_bounds__(256) void redk_ln(
    const float* __restrict__ parts, const float* __restrict__ bias,
    const float* __restrict__ emb, int gate_h, int gate_e,
    int shift_h, int scale_h, int shift_e, int scale_e,
    const float* __restrict__ res_h, const float* __restrict__ res_e,
    float* __restrict__ out_h, float* __restrict__ out_e, bf16_t* __restrict__ xout) {
  int row = blockIdx.x, tid = threadIdx.x;
  const float* res; float* out; int g, sh, sc; int r2;
  if (row < TENC) { res = res_e; out = out_e; g = gate_e; sh = shift_e; sc = scale_e; r2 = row; }
  else            { res = res_h; out = out_h; g = gate_h; sh = shift_h; sc = scale_h; r2 = row - TENC; }
  float v[10], s = 0.f, s2 = 0.f;
  #pragma unroll
  for (int i = 0; i < 10; ++i) {
    int c = tid + i * 256;
    float val = bias[c];
    #pragma unroll
    for (int p = 0; p < P; ++p) val += parts[(size_t)p * SEQ * D + (size_t)row * D + c];
    val = res[(size_t)r2 * D + c] + val * emb[(size_t)g * D + c];
    out[(size_t)r2 * D + c] = val;
    v[i] = val; s += val; s2 += val * val;
  }
  #pragma unroll
  for (int o = 32; o > 0; o >>= 1) { s += __shfl_down(s, o); s2 += __shfl_down(s2, o); }
  __shared__ float red[8];
  int wvv = tid >> 6, lnn = tid & 63;
  if (lnn == 0) { red[wvv] = s; red[4 + wvv] = s2; }
  __syncthreads();
  s  = red[0] + red[1] + red[2] + red[3];
  s2 = red[4] + red[5] + red[6] + red[7];
  float mean = s * (1.f / D);
  float rstd = rsqrtf(s2 * (1.f / D) - mean * mean + 1e-5f);
  #pragma unroll
  for (int i = 0; i < 10; ++i) {
    int c = tid + i * 256;
    xout[(size_t)row * D + c] =
        (bf16_t)((v[i] - mean) * rstd * (1.f + emb[(size_t)sc * D + c]) + emb[(size_t)sh * D + c]);
  }
}

// ---------------- per-head LN (+RoPE rows>=128); f32 [h][r][40] -> bf16 [h][r][64] zero-padded
__global__ void qk_post(const float* __restrict__ qh, const float* __restrict__ kh,
                        const float* __restrict__ rc, const float* __restrict__ rs,
                        bf16_t* __restrict__ qb, bf16_t* __restrict__ kb) {
  int r = blockIdx.x * 128 + threadIdx.x;  // 0..1151
  int h = blockIdx.y;
  float cs[HD], sn[HD];
  bool rope = (r >= TENC);
  if (rope) {
    const float* cp = rc + (size_t)(r - TENC) * HD;
    const float* sp = rs + (size_t)(r - TENC) * HD;
    #pragma unroll
    for (int d = 0; d < HD; ++d) { cs[d] = cp[d]; sn[d] = sp[d]; }
  }
  #pragma unroll
  for (int which = 0; which < 2; ++which) {
    const float* base = (which == 0 ? qh : kh) + (size_t)h * SEQ * HD + (size_t)r * HD;
    bf16_t* dst = (which == 0 ? qb : kb) + ((size_t)h * SEQ + r) * 64;
    float v[HD], s = 0.f, s2 = 0.f;
    #pragma unroll
    for (int d = 0; d < HD; ++d) { v[d] = base[d]; s += v[d]; }
    float mean = s * (1.f / HD);
    #pragma unroll
    for (int d = 0; d < HD; ++d) { float x = v[d] - mean; v[d] = x; s2 += x * x; }
    float rstd = rsqrtf(s2 * (1.f / HD) + 1e-5f);
    #pragma unroll
    for (int d = 0; d < HD; ++d) v[d] *= rstd;
    if (rope) {
      #pragma unroll
      for (int d = 0; d < HD / 2; ++d) {
        float lo = v[d], hi = v[d + 20];
        v[d]      = lo * cs[d]      - hi * sn[d];
        v[d + 20] = hi * cs[d + 20] + lo * sn[d + 20];
      }
    }
    float qs = (which == 0) ? 0.15811388300841897f : 1.f;  // 1/sqrt(40)
    #pragma unroll
    for (int d = 0; d < HD; ++d) dst[d] = (bf16_t)(v[d] * qs);
    #pragma unroll
    for (int d = HD; d < 64; ++d) dst[d] = (bf16_t)0.f;
  }
}

// ---------------- MFMA flash attention: block = (64 q-rows, head), 4 waves x 16 q-rows
__global__ __launch_bounds__(256) void attn_mfma(
    const bf16_t* __restrict__ qb, const bf16_t* __restrict__ kb,
    const bf16_t* __restrict__ vt, bf16_t* __restrict__ obf) {
  __shared__ bf16_t Ks[64 * 64];
  __shared__ bf16_t Vs[48 * 64];
  __shared__ bf16_t Ps[4][16 * 64];
  const int h = blockIdx.y;
  const int tid = threadIdx.x, wv = tid >> 6, ln = tid & 63;
  const int qbase = blockIdx.x * 64 + wv * 16;
  const int lr = ln & 15, lg = ln >> 4;

  bf16x8 af[2];
  {
    const bf16_t* qp = qb + ((size_t)h * SEQ + qbase + lr) * 64 + lg * 8;
    af[0] = *(const bf16x8*)(qp);
    af[1] = *(const bf16x8*)(qp + 32);
  }
  const f32x4 zero = {0.f, 0.f, 0.f, 0.f};
  f32x4 acc[3];
  acc[0] = zero; acc[1] = zero; acc[2] = zero;
  float mrow[4], lrow[4];
  #pragma unroll
  for (int r = 0; r < 4; ++r) { mrow[r] = -1e30f; lrow[r] = 0.f; }

  const bf16_t* kbh = kb + (size_t)h * SEQ * 64;
  const bf16_t* vth = vt + (size_t)h * 48 * SEQ;

  for (int kv0 = 0; kv0 < SEQ; kv0 += 64) {
    __syncthreads();
    #pragma unroll
    for (int i = 0; i < 2; ++i) {
      int g = wv * 2 + i;
      int slot = g * 64 + ln;
      int kr = slot >> 3, so = slot & 7;
      gld_lds16(kbh + (size_t)(kv0 + kr) * 64 + ((so ^ (kr & 7)) << 3), &Ks[g * 512]);
    }
    #pragma unroll
    for (int i = 0; i < 2; ++i) {
      int g = wv + 4 * i;
      if (g < 6) {
        int slot = g * 64 + ln;
        int dr = slot >> 3, so = slot & 7;
        gld_lds16(vth + (size_t)dr * SEQ + kv0 + ((so ^ (dr & 7)) << 3), &Vs[g * 512]);
      }
    }
    __syncthreads();
    f32x4 s[4];
    #pragma unroll
    for (int nt = 0; nt < 4; ++nt) {
      s[nt] = zero;
      int kvr = nt * 16 + lr;
      #pragma unroll
      for (int kk = 0; kk < 2; ++kk) {
        bf16x8 bk = *(const bf16x8*)&Ks[kvr * 64 + (((kk * 4 + lg) ^ (kvr & 7)) << 3)];
        s[nt] = __builtin_amdgcn_mfma_f32_16x16x32_bf16(af[kk], bk, s[nt], 0, 0, 0);
      }
    }
    float pn[4][4];
    #pragma unroll
    for (int r = 0; r < 4; ++r) {
      float tm = fmaxf(fmaxf(s[0][r], s[1][r]), fmaxf(s[2][r], s[3][r]));
      #pragma unroll
      for (int o = 8; o > 0; o >>= 1) tm = fmaxf(tm, __shfl_xor(tm, o));
      float mn = fmaxf(mrow[r], tm);
      float scl = __expf(mrow[r] - mn);
      mrow[r] = mn;
      float ts = 0.f;
      #pragma unroll
      for (int nt = 0; nt < 4; ++nt) { pn[nt][r] = __expf(s[nt][r] - mn); ts += pn[nt][r]; }
      #pragma unroll
      for (int o = 8; o > 0; o >>= 1) ts += __shfl_xor(ts, o);
      lrow[r] = lrow[r] * scl + ts;
      acc[0][r] *= scl; acc[1][r] *= scl; acc[2][r] *= scl;
    }
    #pragma unroll
    for (int nt = 0; nt < 4; ++nt)
      #pragma unroll
      for (int r = 0; r < 4; ++r) {
        int q = lg * 4 + r;
        int kv = nt * 16 + lr;
        Ps[wv][q * 64 + ((((kv >> 3) ^ (q & 7)) << 3) | (kv & 7))] = (bf16_t)pn[nt][r];
      }
    bf16x8 pa[2];
    #pragma unroll
    for (int kk = 0; kk < 2; ++kk)
      pa[kk] = *(const bf16x8*)&Ps[wv][lr * 64 + (((kk * 4 + lg) ^ (lr & 7)) << 3)];
    #pragma unroll
    for (int dt = 0; dt < 3; ++dt) {
      #pragma unroll
      for (int kk = 0; kk < 2; ++kk) {
        int dr = dt * 16 + lr;
        bf16x8 bv = *(const bf16x8*)&Vs[dr * 64 + (((kk * 4 + lg) ^ (dr & 7)) << 3)];
        acc[dt] = __builtin_amdgcn_mfma_f32_16x16x32_bf16(pa[kk], bv, acc[dt], 0, 0, 0);
      }
    }
  }
  #pragma unroll
  for (int dt = 0; dt < 3; ++dt) {
    int d = dt * 16 + lr;
    if (d < HD) {
      #pragma unroll
      for (int r = 0; r < 4; ++r) {
        int q = qbase + lg * 4 + r;
        obf[(size_t)q * D + h * HD + d] = (bf16_t)(acc[dt][r] / lrow[r]);
      }
    }
  }
}

extern "C" void kernel_launch(void* const* d_in, const int* in_sizes, int n_in,
                              void* d_out, int out_size, void* d_ws, size_t ws_size,
                              hipStream_t stream) {
  const float* hid = (const float*)d_in[0];
  const float* enc = (const float*)d_in[1];
  const float* tem = (const float*)d_in[2];
  const float* rc  = (const float*)d_in[3];
  const float* rs  = (const float*)d_in[4];
  const float* aw  = (const float*)d_in[5];
  const float* ab  = (const float*)d_in[6];
  const float* wq  = (const float*)d_in[7];
  const float* bq  = (const float*)d_in[8];
  const float* wk  = (const float*)d_in[9];
  const float* bk  = (const float*)d_in[10];
  const float* wvv = (const float*)d_in[11];
  const float* bv  = (const float*)d_in[12];
  const float* wo  = (const float*)d_in[13];
  const float* bo  = (const float*)d_in[14];
  const float* w1  = (const float*)d_in[15];
  const float* b1  = (const float*)d_in[16];
  const float* w2  = (const float*)d_in[17];
  const float* b2  = (const float*)d_in[18];
  float* out_hid = (float*)d_out;
  float* out_enc = out_hid + (size_t)THID * D;

  char* ws = (char*)d_ws;
  size_t off = 0;
  auto alloc = [&](size_t b) { char* p = ws + off; off += (b + 255) & ~(size_t)255; return p; };
  float*  emb  = (float*) alloc((size_t)12 * D * 4);
  bf16_t* xln  = (bf16_t*)alloc((size_t)SEQ * D * 2);          // also attn-out bf16
  float*  qh   = (float*) alloc((size_t)NH * SEQ * HD * 4);    // f32 Q head layout; +kh = FF1 act
  float*  kh   = (float*) alloc((size_t)NH * SEQ * HD * 4);
  bf16_t* vt   = (bf16_t*)alloc((size_t)NH * 48 * SEQ * 2);    // V^T bf16, d padded to 48
  bf16_t* qbb  = (bf16_t*)alloc((size_t)NH * SEQ * 64 * 2);    // Q bf16 padded; +kbb = h1/e1 after attn
  bf16_t* kbb  = (bf16_t*)alloc((size_t)NH * SEQ * 64 * 2);
  bf16_t* wqkvT= (bf16_t*)alloc((size_t)3 * D * D * 2);        // [7680][2560] (39.3 MB)
  bf16_t* woT  = (bf16_t*)alloc((size_t)D * D * 2);            // contiguous after wqkvT
  bf16_t* w1T  = (bf16_t*)alloc((size_t)FFD * D * 2);          // [10240][2560]
  bf16_t* w2T  = (bf16_t*)alloc((size_t)D * FFD * 2);          // [2560][10240]
  float*  bqkv = (float*) alloc((size_t)3 * D * 4);
  bf16_t* obf = xln;
  bf16_t* aff = (bf16_t*)qh;          // FF1 activation (qh+kh dead after qk_post)
  float*  h1  = (float*)qbb;          // residual-1 hid (qbb/kbb dead after attn)
  float*  e1  = h1 + (size_t)THID * D;
  float*  oparts = (float*)wqkvT;     // O-proj partials 2x11.8MB (wqkvT dead after QKV)
  float*  fparts = (float*)wqkvT;     // FF2 partials 4x11.8MB (spills into dead woT)

  // L1: ada + wq/wk/wv/wo transposes + bias concat + vt zero (one fused grid)
  prep1<<<dim3(8278), dim3(256), 0, stream>>>(tem, aw, ab, emb, wq, wk, wvv, wo,
      wqkvT, woT, bq, bk, bv, bqkv, vt);
  // L2: LN+mod #1
  ln_mod<<<dim3(SEQ), dim3(256), 0, stream>>>(hid, enc, emb, xln, 0, 2, 1, 3);
  // L3: QKV fused GEMM (540 blocks) + w1T (6400) + w2T (6400) riding along
  qkv_plus<<<dim3(13340), dim3(256), 0, stream>>>(xln, wqkvT, bqkv, qh, kh, vt,
      w1, w1T, w2, w2T);
  // L4: per-head LN + RoPE -> bf16
  qk_post<<<dim3(9, 64), dim3(128), 0, stream>>>(qh, kh, rc, rs, qbb, kbb);
  // L5: attention
  attn_mfma<<<dim3(18, 64), dim3(256), 0, stream>>>(qbb, kbb, vt, obf);
  // L6: O-proj split-K x2 -> partials
  gemm4<4><<<dim3(360), dim3(256), 0, stream>>>(obf, woT, nullptr, D, 20, D, 9, 180,
      nullptr, nullptr, nullptr, nullptr, oparts);
  // L7: reduce + gate + residual -> h1/e1, fused with LN+mod #2 -> xln
  redk_ln<2><<<dim3(SEQ), dim3(256), 0, stream>>>(oparts, bo, emb, 4, 5, 6, 8, 7, 9,
      hid, enc, h1, e1, xln);
  // L8: FF1
  gemm4<1><<<dim3(720), dim3(256), 0, stream>>>(xln, w1T, b1, D, 40, FFD, 9, 720,
      nullptr, nullptr, nullptr, aff, nullptr);
  // L9: FF2 split-K x4 -> partials
  gemm4<4><<<dim3(720), dim3(256), 0, stream>>>(aff, w2T, nullptr, FFD, 40, D, 9, 180,
      nullptr, nullptr, nullptr, nullptr, fparts);
  // L10: final reduce + gate + residual -> d_out
  redk<4><<<dim3(2880), dim3(256), 0, stream>>>(fparts, b2, emb, 10, 11, h1, e1, out_hid, out_enc);
}